// Round 6
// baseline (368.358 us; speedup 1.0000x reference)
//
#include <hip/hip_runtime.h>
#include <cstdint>
#include <cstddef>

typedef __bf16 bf16_t;
typedef __attribute__((ext_vector_type(4))) __bf16 bf16x4_t;
typedef __attribute__((ext_vector_type(8))) __bf16 bf16x8_t;
typedef __attribute__((ext_vector_type(4))) float f32x4_t;

#define T_TOK   4096
#define IN_DIM  4096
#define OUT_DIM 4096
#define K2      320    // 256 hk cols | 8 w cols | 1 shared_b col | 55 zero pad (5x BK=64 tiles)
#define KSPLIT  8      // gate split-K (512 wide)
#define NT_TILES 69    // 64 main K-tiles (4096/64) + 5 tail tiles (320/64)

#define XSZ ((size_t)T_TOK * IN_DIM)
#define WSZ ((size_t)OUT_DIM * IN_DIM)
#define VSZ ((size_t)256 * IN_DIM)
#define NGATE  512                           // gate blocks (64 tgrp x KSPLIT)
#define NB2T_B 512                           // b2t blocks (8 o each)
#define NCAST  ((XSZ + WSZ + VSZ) / 16384)   // 2112 cast blocks (16K floats each)

__device__ __forceinline__ void gload_lds16(const bf16_t* g, bf16_t* l) {
  __builtin_amdgcn_global_load_lds(
      (__attribute__((address_space(1))) void*)(g),
      (__attribute__((address_space(3))) void*)(l), 16, 0, 0);
}

// ===== K1: uber-kernel — gate partials | B2t build | fp32->bf16 casts ======
// R3-verified form: gate LDS 17.4 KB, X/W/V casts in the block sea.
__global__ __launch_bounds__(256) void k1_prep(const float* __restrict__ x,
                                               const float* __restrict__ gw,
                                               const float* __restrict__ sw,
                                               const float* __restrict__ svh,
                                               const float* __restrict__ u,
                                               const float* __restrict__ eb,
                                               const float* __restrict__ sb,
                                               bf16_t* __restrict__ Xbf,
                                               bf16_t* __restrict__ Wbf,
                                               bf16_t* __restrict__ Vbf,
                                               bf16_t* __restrict__ B2t,
                                               float* __restrict__ part) {
  __shared__ __align__(16) float GateLds[32 * 68 * 2];  // 17.4 KB
  const int bid = blockIdx.x;
  const int tid = threadIdx.x;

  if (bid < NGATE) {
    // ---- fp32 gate matmul partials (router precision) ----
    float* Xs = GateLds;            // [kk][t] stride 68
    float* Gs = GateLds + 32 * 68;  // [kk][r]
    const int tbase = (bid & 63) * 64;
    const int kbase = (bid >> 6) * (IN_DIM / KSPLIT);
    const int tg = tid & 15;
    const int rg = tid >> 4;
    float acc[4][4] = {{0.f}};

    for (int cc = 0; cc < (IN_DIM / KSPLIT) / 32; ++cc) {  // 16 chunks of K=32
      const int kc = kbase + cc * 32;
      __syncthreads();
#pragma unroll
      for (int j = 0; j < 2; ++j) {
        const int f = tid * 8 + j * 4;          // [0, 2048)
        const int tt = f >> 5, k4 = f & 31;
        float4 xv = *(const float4*)&x[(size_t)(tbase + tt) * IN_DIM + kc + k4];
        Xs[(k4 + 0) * 68 + tt] = xv.x; Xs[(k4 + 1) * 68 + tt] = xv.y;
        Xs[(k4 + 2) * 68 + tt] = xv.z; Xs[(k4 + 3) * 68 + tt] = xv.w;
        float4 gv = *(const float4*)&gw[(size_t)tt * IN_DIM + kc + k4];
        Gs[(k4 + 0) * 68 + tt] = gv.x; Gs[(k4 + 1) * 68 + tt] = gv.y;
        Gs[(k4 + 2) * 68 + tt] = gv.z; Gs[(k4 + 3) * 68 + tt] = gv.w;
      }
      __syncthreads();
#pragma unroll 4
      for (int kk = 0; kk < 32; ++kk) {
        float4 xv = *(const float4*)&Xs[kk * 68 + tg * 4];
        float4 gv = *(const float4*)&Gs[kk * 68 + rg * 4];
        float xa[4] = {xv.x, xv.y, xv.z, xv.w};
        float ga[4] = {gv.x, gv.y, gv.z, gv.w};
#pragma unroll
        for (int i = 0; i < 4; ++i)
#pragma unroll
          for (int j = 0; j < 4; ++j) acc[i][j] = fmaf(xa[i], ga[j], acc[i][j]);
      }
    }
    const int ks = bid >> 6;
#pragma unroll
    for (int i = 0; i < 4; ++i) {
      float4 o4 = make_float4(acc[i][0], acc[i][1], acc[i][2], acc[i][3]);
      *(float4*)&part[((size_t)ks * T_TOK + tbase + tg * 4 + i) * 64 + rg * 4] = o4;
    }
  } else if (bid < NGATE + NB2T_B) {
    // ---- B2t[o][c] = u[e][o][k] | eb[e][o] | sb[o] | 0  (8 o per block) ----
    const int o = (bid - NGATE) * 8 + (tid >> 5);
    for (int c = tid & 31; c < K2; c += 32) {
      float v;
      if (c < 256)       v = u[((size_t)(c >> 5) * OUT_DIM + o) * 32 + (c & 31)];
      else if (c < 264)  v = eb[(size_t)(c - 256) * OUT_DIM + o];
      else if (c == 264) v = sb[o];
      else               v = 0.f;
      B2t[(size_t)o * K2 + c] = (__bf16)v;
    }
  } else {
    // ---- casts: x->Xbf, sw->Wbf, svh->Vbf (16384 floats/block, 16 rounds) --
    size_t base = (size_t)(bid - NGATE - NB2T_B) * 16384;
    const float* src; bf16_t* dst; size_t i0;
    if (base < XSZ)            { src = x;   dst = Xbf; i0 = base; }
    else if (base < XSZ + WSZ) { src = sw;  dst = Wbf; i0 = base - XSZ; }
    else                       { src = svh; dst = Vbf; i0 = base - XSZ - WSZ; }
#pragma unroll
    for (int j = 0; j < 16; ++j) {
      size_t i = i0 + (size_t)j * 1024 + (size_t)tid * 4;
      float4 v = *(const float4*)(src + i);
      bf16x4_t o;
      o[0] = (__bf16)v.x; o[1] = (__bf16)v.y; o[2] = (__bf16)v.z; o[3] = (__bf16)v.w;
      *(bf16x4_t*)(dst + i) = o;
    }
  }
}

// ===== K23: fused hk GEMM + router + A2 assembly ===========================
// Block = 32 tokens x all 256 hk cols, full K=4096 in-register (no split-K,
// no hkp). K4's verified 2-phase counted-vmcnt pipeline, scaled: 256 thr
// (4 waves, 1M x 4N), BK=64, 9 gload_lds/tile -> vmcnt(9). Epilogue computes
// router weights from part (fp32) and writes A2 = hk*w | w | 1 | 0 directly.
__global__ __launch_bounds__(256) void k23_hk_router(
    const bf16_t* __restrict__ X, const bf16_t* __restrict__ V,
    const float* __restrict__ part, bf16_t* __restrict__ A2) {
  __shared__ __align__(16) bf16_t As[2][32 * 64];    // 4 KB each
  __shared__ __align__(16) bf16_t Bs[2][256 * 64];   // 32 KB each
  __shared__ float rl[32 * 8];
  __shared__ float wls[32 * 8];
  const int tid = threadIdx.x;
  const int w = tid >> 6, l = tid & 63;
  const int tbase = blockIdx.x * 32;
  const int lr = l & 15, lk = (l >> 4) * 8;

  // swizzled ds_read byte offsets (row stride 128B; swz = (row&7)<<4)
  int aoff[2], boff[4];
#pragma unroll
  for (int mi = 0; mi < 2; ++mi) {
    const int row = mi * 16 + lr;
    aoff[mi] = row * 128 + ((lk * 2) ^ ((row & 7) << 4));
  }
#pragma unroll
  for (int ni = 0; ni < 4; ++ni) {
    const int row = w * 64 + ni * 16 + lr;
    boff[ni] = row * 128 + ((lk * 2) ^ ((row & 7) << 4));
  }

  f32x4_t acc[2][4];
#pragma unroll
  for (int i = 0; i < 2; ++i)
#pragma unroll
    for (int j = 0; j < 4; ++j) { f32x4_t z = {0.f, 0.f, 0.f, 0.f}; acc[i][j] = z; }

  // stage: A (32x64, 1 issue/wave) + B (256x64, 8 issues/wave) = 9 per tile.
  const int row8 = l >> 3;                           // 0..7
  const int scol = ((l & 7) ^ (row8 & 7)) << 3;      // pre-swizzled source col
  auto stage = [&](int kt, int buf) {
    const bf16_t* gA = X + (size_t)(tbase + w * 8 + row8) * IN_DIM + kt * 64 + scol;
    gload_lds16(gA, &As[buf][(w * 8) * 64]);
    const bf16_t* gB = V + (size_t)(w * 8 + row8) * IN_DIM + kt * 64 + scol;
#pragma unroll
    for (int j = 0; j < 8; ++j)
      gload_lds16(gB + (size_t)(j * 32) * IN_DIM, &Bs[buf][(j * 32 + w * 8) * 64]);
  };

  stage(0, 0);
  stage(1, 1);
  asm volatile("s_waitcnt vmcnt(9)\n\ts_barrier" ::: "memory");

  int cur = 0;
  for (int kt = 0; kt < 64; ++kt) {
    const char* Ab = (const char*)&As[cur][0];
    const char* Bb = (const char*)&Bs[cur][0];
    bf16x8_t a0[2], p0[4], a1[2], p1[4];
#pragma unroll
    for (int mi = 0; mi < 2; ++mi) a0[mi] = *(const bf16x8_t*)(Ab + aoff[mi]);
#pragma unroll
    for (int ni = 0; ni < 4; ++ni) p0[ni] = *(const bf16x8_t*)(Bb + boff[ni]);
    __builtin_amdgcn_s_setprio(1);
#pragma unroll
    for (int mi = 0; mi < 2; ++mi)
#pragma unroll
      for (int ni = 0; ni < 4; ++ni)
        acc[mi][ni] = __builtin_amdgcn_mfma_f32_16x16x32_bf16(a0[mi], p0[ni], acc[mi][ni], 0, 0, 0);
    __builtin_amdgcn_s_setprio(0);
#pragma unroll
    for (int mi = 0; mi < 2; ++mi) a1[mi] = *(const bf16x8_t*)(Ab + (aoff[mi] ^ 64));
#pragma unroll
    for (int ni = 0; ni < 4; ++ni) p1[ni] = *(const bf16x8_t*)(Bb + (boff[ni] ^ 64));
    asm volatile("s_waitcnt lgkmcnt(0)\n\ts_barrier" ::: "memory");
    stage(kt + 2 < 64 ? kt + 2 : 63, cur);
    __builtin_amdgcn_s_setprio(1);
#pragma unroll
    for (int mi = 0; mi < 2; ++mi)
#pragma unroll
      for (int ni = 0; ni < 4; ++ni)
        acc[mi][ni] = __builtin_amdgcn_mfma_f32_16x16x32_bf16(a1[mi], p1[ni], acc[mi][ni], 0, 0, 0);
    __builtin_amdgcn_s_setprio(0);
    asm volatile("s_waitcnt vmcnt(9)\n\ts_barrier" ::: "memory");
    cur ^= 1;
  }
  asm volatile("s_waitcnt vmcnt(0)" ::: "memory");
  __syncthreads();

  // ---- router phase A: thread (tt = tid>>3, e = tid&7) ----
  {
    const int tt = tid >> 3, e = tid & 7;
    float s2 = 0.f;
#pragma unroll
    for (int j = 0; j < 8; ++j) {
      float s = 0.f;
#pragma unroll
      for (int ks = 0; ks < KSPLIT; ++ks)
        s += part[((size_t)ks * T_TOK + tbase + tt) * 64 + e * 8 + j];
      s2 += s * s;
    }
    rl[tt * 8 + e] = sqrtf(s2);
  }
  __syncthreads();
  if (tid < 32) {
    const int tt = tid;
    float r0[8];
#pragma unroll
    for (int e = 0; e < 8; ++e) r0[e] = rl[tt * 8 + e];
    int e1 = 0; float v1 = r0[0];
#pragma unroll
    for (int e = 1; e < 8; ++e) if (r0[e] > v1) { v1 = r0[e]; e1 = e; }
    int e2 = -1; float v2 = -1e30f;
#pragma unroll
    for (int e = 0; e < 8; ++e) if (e != e1 && r0[e] > v2) { v2 = r0[e]; e2 = e; }
    float w1 = 1.f / (1.f + expf(v2 - v1));
#pragma unroll
    for (int e = 0; e < 8; ++e) wls[tt * 8 + e] = 0.f;
    wls[tt * 8 + e1] = w1; wls[tt * 8 + e2] = 1.f - w1;
  }
  __syncthreads();

  // ---- A2 writes: hk*w from acc | w | 1.0 | 0 pad ----
  const int row0 = (l >> 4) * 4;   // C/D: col = lane&15, row = (lane>>4)*4 + r
#pragma unroll
  for (int mi = 0; mi < 2; ++mi) {
    const int m = mi * 16 + row0;
#pragma unroll
    for (int ni = 0; ni < 4; ++ni) {
      const int c = w * 64 + ni * 16 + lr;
      const int e = c >> 5;
      f32x4_t v = acc[mi][ni];
#pragma unroll
      for (int r = 0; r < 4; ++r)
        A2[(size_t)(tbase + m + r) * K2 + c] = (__bf16)(v[r] * wls[(m + r) * 8 + e]);
    }
  }
  {
    const int t = tid >> 3, e = tid & 7;
    A2[(size_t)(tbase + t) * K2 + 256 + e] = (__bf16)wls[t * 8 + e];
    for (int c = 265 + e; c < K2; c += 8)
      A2[(size_t)(tbase + t) * K2 + c] = (__bf16)0.f;
  }
  if (tid < 32) A2[(size_t)(tbase + tid) * K2 + 264] = (__bf16)1.0f;
}

// ===== K4: fused GEMM: out = Xbf.Wbf^T (K=4096) + A2.B2t^T (K=320) =========
// R1-verified structure: 256x256 tile, BK=64, 8 waves (2Mx4N), 2 phases/tile,
// double-buffered 128 KiB LDS, raw s_barrier + counted vmcnt(8), XOR
// bank-swizzle, setprio around MFMA clusters, XCD-chunked block map.
__global__ __launch_bounds__(512, 2) void gemm_fused(
    const bf16_t* __restrict__ X, const bf16_t* __restrict__ W,
    const bf16_t* __restrict__ A2, const bf16_t* __restrict__ B2t,
    float* __restrict__ out) {
  __shared__ __align__(16) bf16_t As[2][256 * 64];   // 64 KiB
  __shared__ __align__(16) bf16_t Bs[2][256 * 64];   // 64 KiB
  const int tid = threadIdx.x;
  const int w = tid >> 6, l = tid & 63;
  // T1: chunked XCD swizzle — 256 blocks, 32 contiguous tiles per XCD
  const int nb = (blockIdx.x & 7) * 32 + (blockIdx.x >> 3);
  const int mBase = (nb >> 4) * 256, nBase = (nb & 15) * 256;
  const int wm = w >> 2, wn = w & 3;                 // 2M x 4N wave grid
  const int lr = l & 15, lk = (l >> 4) * 8;

  // swizzled ds_read byte offsets (row stride 128B; swz = (row&7)<<4)
  int aoff[8], boff[4];
#pragma unroll
  for (int mi = 0; mi < 8; ++mi) {
    const int row = wm * 128 + mi * 16 + lr;
    aoff[mi] = row * 128 + ((lk * 2) ^ ((row & 7) << 4));
  }
#pragma unroll
  for (int ni = 0; ni < 4; ++ni) {
    const int row = wn * 64 + ni * 16 + lr;
    boff[ni] = row * 128 + ((lk * 2) ^ ((row & 7) << 4));
  }

  f32x4_t acc[8][4];
#pragma unroll
  for (int i = 0; i < 8; ++i)
#pragma unroll
    for (int j = 0; j < 4; ++j) { f32x4_t z = {0.f, 0.f, 0.f, 0.f}; acc[i][j] = z; }

  auto stage = [&](int kt, int buf) {
    const int rsub = w * 8 + (l >> 3);
    const int scol = ((l & 7) ^ ((l >> 3) & 7)) << 3;
    bf16_t* lA = &As[buf][w * 512];
    bf16_t* lB = &Bs[buf][w * 512];
    if (kt < 64) {
      const bf16_t* gA = X + (size_t)(mBase + rsub) * IN_DIM + kt * 64 + scol;
      const bf16_t* gB = W + (size_t)(nBase + rsub) * IN_DIM + kt * 64 + scol;
#pragma unroll
      for (int i = 0; i < 4; ++i) {
        gload_lds16(gA + (size_t)(i * 64) * IN_DIM, lA + i * 4096);
        gload_lds16(gB + (size_t)(i * 64) * IN_DIM, lB + i * 4096);
      }
    } else {
      const int koff = (kt - 64) * 64;
      const bf16_t* gA = A2 + (size_t)(mBase + rsub) * K2 + koff + scol;
      const bf16_t* gB = B2t + (size_t)(nBase + rsub) * K2 + koff + scol;
#pragma unroll
      for (int i = 0; i < 4; ++i) {
        gload_lds16(gA + (size_t)(i * 64) * K2, lA + i * 4096);
        gload_lds16(gB + (size_t)(i * 64) * K2, lB + i * 4096);
      }
    }
  };

  stage(0, 0);
  stage(1, 1);
  asm volatile("s_waitcnt vmcnt(8)\n\ts_barrier" ::: "memory");

  int cur = 0;
  for (int kt = 0; kt < NT_TILES; ++kt) {
    const char* Ab = (const char*)&As[cur][0];
    const char* Bb = (const char*)&Bs[cur][0];
    bf16x8_t a0[8], p0[4], a1[8], p1[4];
#pragma unroll
    for (int mi = 0; mi < 8; ++mi) a0[mi] = *(const bf16x8_t*)(Ab + aoff[mi]);
#pragma unroll
    for (int ni = 0; ni < 4; ++ni) p0[ni] = *(const bf16x8_t*)(Bb + boff[ni]);
    __builtin_amdgcn_s_setprio(1);
#pragma unroll
    for (int mi = 0; mi < 8; ++mi)
#pragma unroll
      for (int ni = 0; ni < 4; ++ni)
        acc[mi][ni] = __builtin_amdgcn_mfma_f32_16x16x32_bf16(a0[mi], p0[ni], acc[mi][ni], 0, 0, 0);
    __builtin_amdgcn_s_setprio(0);
#pragma unroll
    for (int mi = 0; mi < 8; ++mi) a1[mi] = *(const bf16x8_t*)(Ab + (aoff[mi] ^ 64));
#pragma unroll
    for (int ni = 0; ni < 4; ++ni) p1[ni] = *(const bf16x8_t*)(Bb + (boff[ni] ^ 64));
    asm volatile("s_waitcnt lgkmcnt(0)\n\ts_barrier" ::: "memory");
    stage(kt + 2 < NT_TILES ? kt + 2 : NT_TILES - 1, cur);
    __builtin_amdgcn_s_setprio(1);
#pragma unroll
    for (int mi = 0; mi < 8; ++mi)
#pragma unroll
      for (int ni = 0; ni < 4; ++ni)
        acc[mi][ni] = __builtin_amdgcn_mfma_f32_16x16x32_bf16(a1[mi], p1[ni], acc[mi][ni], 0, 0, 0);
    __builtin_amdgcn_s_setprio(0);
    asm volatile("s_waitcnt vmcnt(8)\n\ts_barrier" ::: "memory");
    cur ^= 1;
  }
  asm volatile("s_waitcnt vmcnt(0)" ::: "memory");

  const int row0 = (l >> 4) * 4;  // C/D: col = lane&15, row = (lane>>4)*4 + r
#pragma unroll
  for (int mi = 0; mi < 8; ++mi) {
    const int m = mBase + wm * 128 + mi * 16 + row0;
#pragma unroll
    for (int ni = 0; ni < 4; ++ni) {
      const int n = nBase + wn * 64 + ni * 16 + lr;
      f32x4_t v = acc[mi][ni];
#pragma unroll
      for (int r = 0; r < 4; ++r) out[(size_t)(m + r) * OUT_DIM + n] = v[r];
    }
  }
}

extern "C" void kernel_launch(void* const* d_in, const int* in_sizes, int n_in,
                              void* d_out, int out_size, void* d_ws, size_t ws_size,
                              hipStream_t stream) {
  const float* x   = (const float*)d_in[0];
  const float* gw  = (const float*)d_in[1];
  const float* sw  = (const float*)d_in[2];
  const float* sb  = (const float*)d_in[3];
  const float* u   = (const float*)d_in[4];
  const float* svh = (const float*)d_in[5];
  const float* eb  = (const float*)d_in[6];
  float* out = (float*)d_out;

  char* ws = (char*)d_ws;
  size_t off = 0;
  auto carve = [&](size_t bytes) {
    void* p = ws + off;
    off = (off + bytes + 255) & ~(size_t)255;
    return p;
  };
  bf16_t* Xbf = (bf16_t*)carve(XSZ * 2);
  bf16_t* Wbf = (bf16_t*)carve(WSZ * 2);
  bf16_t* Vbf = (bf16_t*)carve(VSZ * 2);
  float*  part = (float*)carve((size_t)KSPLIT * T_TOK * 64 * 4);
  bf16_t* A2   = (bf16_t*)carve((size_t)T_TOK * K2 * 2);
  bf16_t* B2t  = (bf16_t*)carve((size_t)OUT_DIM * K2 * 2);
  (void)ws_size; (void)in_sizes; (void)n_in; (void)out_size;

  // K1: gate partials + B2t + all casts in one launch (R3-verified)
  k1_prep<<<(int)(NGATE + NB2T_B + NCAST), 256, 0, stream>>>(
      x, gw, sw, svh, u, eb, sb, Xbf, Wbf, Vbf, B2t, part);

  // K23: fused hk GEMM (full-K, in-register) + router + A2, 128 blocks
  k23_hk_router<<<dim3(128), 256, 0, stream>>>(Xbf, Vbf, part, A2);

  // K4: one fused 256^2 2-phase GEMM (R1-verified) -> d_out
  gemm_fused<<<dim3(256), 512, 0, stream>>>(Xbf, Wbf, A2, B2t, out);
}